// Round 3
// baseline (336.091 us; speedup 1.0000x reference)
//
#include <hip/hip_runtime.h>

#define N_PTS 131072
#define C_DIM 128
#define NS_K  16
#define BN_EPS 1e-5f

typedef unsigned short ushort_t;
typedef unsigned short u16x8 __attribute__((ext_vector_type(8)));
typedef __bf16 bf16x8 __attribute__((ext_vector_type(8)));
typedef float f32x4 __attribute__((ext_vector_type(4)));

__device__ __forceinline__ ushort_t f2b(float f) {
    unsigned int u = __float_as_uint(f);
    u += 0x7FFFu + ((u >> 16) & 1u);          // round-to-nearest-even
    return (ushort_t)(u >> 16);
}
__device__ __forceinline__ float b2f(ushort_t h) {
    return __uint_as_float((unsigned int)h << 16);
}

// ---------------------------------------------------------------------------
// Prep: wT[n][k] = bf16(W[k][n]) for both weight matrices (one-shot, 64 KB).
// ---------------------------------------------------------------------------
__global__ __launch_bounds__(256) void prep_w_kernel(
    const float* __restrict__ W1, const float* __restrict__ W2,
    ushort_t* __restrict__ wT1, ushort_t* __restrict__ wT2)
{
    const int t = blockIdx.x * 256 + threadIdx.x;   // 0..16383
    const int n = t & 127;
    const int k = t >> 7;
    wT1[n * 128 + k] = f2b(W1[k * 128 + n]);
    wT2[n * 128 + k] = f2b(W2[k * 128 + n]);
}

// ---------------------------------------------------------------------------
// MFMA GEMM (gemm1): out_bf16[N,128] = A_f32[N,128] @ W + bias.
// B-fragments read directly from global wT (32 KB, L2-resident) -> no w_sh.
// LDS = 35.8 KB -> 4 blocks/CU; __launch_bounds__(256,4) caps VGPR at 128.
// Fragment layouts (validated): A[m=lane&15][k=q*8+j];
// B[k=q*8+j][n=lane&15] from wT[n][k]; C/D col=lane&15, row=q*4+reg.
// ---------------------------------------------------------------------------
template <bool A_BF16, bool STATS>
__global__ __launch_bounds__(256, 4) void gemm_mfma_kernel(
    const void* __restrict__ Aptr, const ushort_t* __restrict__ wT,
    const float* __restrict__ bias, ushort_t* __restrict__ out,
    float* __restrict__ gsum, float* __restrict__ gsq)
{
    __shared__ __align__(16) ushort_t a_sh[128 * 136];   // A tile, then C tile
    __shared__ float s_sum[128];
    __shared__ float s_sq[128];

    const int tid  = threadIdx.x;
    const int lane = tid & 63;
    const int wv   = tid >> 6;
    const int m16  = lane & 15;
    const int q    = lane >> 4;
    const int base = blockIdx.x * 128;

    if (STATS && tid < 128) { s_sum[tid] = 0.f; s_sq[tid] = 0.f; }

    // ---- stage A tile (128x128, convert f32->bf16 if needed) ----
    {
        const int row  = tid >> 1;
        const int half = (tid & 1) * 64;
        ushort_t* as = a_sh + row * 136 + half;
        if (A_BF16) {
            const ushort_t* ag = (const ushort_t*)Aptr + (size_t)(base + row) * 128 + half;
            #pragma unroll
            for (int j = 0; j < 8; j++)
                *(u16x8*)(as + j * 8) = *(const u16x8*)(ag + j * 8);
        } else {
            const float* ag = (const float*)Aptr + (size_t)(base + row) * 128 + half;
            #pragma unroll
            for (int j = 0; j < 8; j++) {
                f32x4 lo = *(const f32x4*)(ag + j * 8);
                f32x4 hi = *(const f32x4*)(ag + j * 8 + 4);
                u16x8 v;
                v[0] = f2b(lo[0]); v[1] = f2b(lo[1]); v[2] = f2b(lo[2]); v[3] = f2b(lo[3]);
                v[4] = f2b(hi[0]); v[5] = f2b(hi[1]); v[6] = f2b(hi[2]); v[7] = f2b(hi[3]);
                *(u16x8*)(as + j * 8) = v;
            }
        }
    }
    __syncthreads();

    f32x4 acc[2][8];
    #pragma unroll
    for (int i = 0; i < 2; i++)
        #pragma unroll
        for (int c = 0; c < 8; c++) acc[i][c] = (f32x4){0.f, 0.f, 0.f, 0.f};

    const ushort_t* ap0 = a_sh + ((wv * 2 + 0) * 16 + m16) * 136 + q * 8;
    const ushort_t* ap1 = a_sh + ((wv * 2 + 1) * 16 + m16) * 136 + q * 8;
    const ushort_t* wp  = wT + (size_t)m16 * 128 + q * 8;   // row m16, +c*16 rows per tile

    #pragma unroll
    for (int k0 = 0; k0 < 128; k0 += 32) {
        bf16x8 a0 = __builtin_bit_cast(bf16x8, *(const u16x8*)(ap0 + k0));
        bf16x8 a1 = __builtin_bit_cast(bf16x8, *(const u16x8*)(ap1 + k0));
        #pragma unroll
        for (int c = 0; c < 8; c++) {
            bf16x8 b = __builtin_bit_cast(bf16x8, *(const u16x8*)(wp + c * (16 * 128) + k0));
            acc[0][c] = __builtin_amdgcn_mfma_f32_16x16x32_bf16(a0, b, acc[0][c], 0, 0, 0);
            acc[1][c] = __builtin_amdgcn_mfma_f32_16x16x32_bf16(a1, b, acc[1][c], 0, 0, 0);
        }
    }

    __syncthreads();   // all MFMA LDS reads done; a_sh now reusable as C tile

    // ---- epilogue: bias, bf16 -> LDS C tile, BN partial sums ----
    float psum[8], psq[8];
    #pragma unroll
    for (int c = 0; c < 8; c++) { psum[c] = 0.f; psq[c] = 0.f; }

    #pragma unroll
    for (int c = 0; c < 8; c++) {
        const int col = c * 16 + m16;
        const float bv = bias[col];
        #pragma unroll
        for (int i = 0; i < 2; i++) {
            const int rb = (wv * 2 + i) * 16 + q * 4;
            #pragma unroll
            for (int r = 0; r < 4; r++) {
                const float v = acc[i][c][r] + bv;
                a_sh[(rb + r) * 136 + col] = f2b(v);
                if (STATS) { psum[c] += v; psq[c] += v * v; }
            }
        }
    }
    if (STATS) {
        #pragma unroll
        for (int c = 0; c < 8; c++) {
            atomicAdd(&s_sum[c * 16 + m16], psum[c]);
            atomicAdd(&s_sq[c * 16 + m16],  psq[c]);
        }
    }
    __syncthreads();

    // ---- coalesced write-out: 16 lanes cover one 256 B row ----
    {
        const int r0 = tid >> 4;            // 0..15
        const int c0 = (tid & 15) * 8;      // 16 B chunk within row
        #pragma unroll
        for (int it = 0; it < 8; it++) {
            const int rl = r0 + it * 16;
            const u16x8 v = *(const u16x8*)(a_sh + rl * 136 + c0);
            *(u16x8*)(out + (size_t)(base + rl) * 128 + c0) = v;
        }
    }
    if (STATS && tid < 128) {
        atomicAdd(&gsum[tid], s_sum[tid]);
        atomicAdd(&gsq[tid],  s_sq[tid]);
    }
}

// ---------------------------------------------------------------------------
// FUSED: laplacian gather -> A tile in LDS -> MFMA gemm2 -> bias + BN stats.
// Occupancy-first rework: no w_sh (B from global wT, L2-hot), no s_idx
// (indices int4-loaded per point; 16 lanes share one address -> HW merge).
// LDS = 35.8 KB -> 4 blocks/CU; launch_bounds(256,4) -> 16 waves/CU target.
// acc[2][8] only becomes live after the gather barrier (keeps gather-phase
// VGPR pressure ~115 < 128 cap).
// ---------------------------------------------------------------------------
__global__ __launch_bounds__(256, 4) void lap_gemm_kernel(
    const ushort_t* __restrict__ table, const int* __restrict__ idx,
    const ushort_t* __restrict__ wT, const float* __restrict__ bias,
    ushort_t* __restrict__ out, float* __restrict__ gsum, float* __restrict__ gsq)
{
    __shared__ __align__(16) ushort_t a_sh[128 * 136];   // lap tile, then C tile
    __shared__ float s_sum[128];
    __shared__ float s_sq[128];

    const int tid  = threadIdx.x;
    const int lane = tid & 63;
    const int wv   = tid >> 6;
    const int m16  = lane & 15;
    const int q    = lane >> 4;
    const int base = blockIdx.x * 128;

    if (tid < 128) { s_sum[tid] = 0.f; s_sq[tid] = 0.f; }

    // ---- gather + laplacian directly into a_sh (bf16, identical rounding) ----
    {
        const int pl = tid >> 4;            // 0..15: point-in-group
        const int c8 = (tid & 15) * 8;      // 16 B channel chunk
        #pragma unroll 1
        for (int it = 0; it < 8; it++) {
            const int pp = it * 16 + pl;    // local point 0..127
            const size_t prow = (size_t)(base + pp);

            // 16 KNN indices: 4x int4; all 16 lanes of the channel group read
            // the same address -> merged request, L2-hot.
            const int4* ig = (const int4*)(idx + prow * NS_K);
            const int4 i0 = ig[0], i1 = ig[1], i2 = ig[2], i3 = ig[3];
            const int jj[16] = {i0.x, i0.y, i0.z, i0.w, i1.x, i1.y, i1.z, i1.w,
                                i2.x, i2.y, i2.z, i2.w, i3.x, i3.y, i3.z, i3.w};

            const u16x8 cv = *(const u16x8*)(table + prow * 128 + c8);
            float ctr[8];
            #pragma unroll
            for (int e = 0; e < 8; e++) ctr[e] = b2f(cv[e]);

            float lacc[8];
            #pragma unroll
            for (int e = 0; e < 8; e++) lacc[e] = 0.f;

            #pragma unroll
            for (int s = 0; s < NS_K; s++) {
                const u16x8 nv = *(const u16x8*)(table + (size_t)jj[s] * 128 + c8);
                #pragma unroll
                for (int e = 0; e < 8; e++)
                    lacc[e] += fmaxf(b2f(nv[e]) - ctr[e], 0.f);
            }
            u16x8 ov;
            #pragma unroll
            for (int e = 0; e < 8; e++) ov[e] = f2b(lacc[e] * (1.f / (float)NS_K));
            *(u16x8*)(a_sh + pp * 136 + c8) = ov;
        }
    }
    __syncthreads();

    // ---- MFMA: h = lap @ W2 (B direct from global wT) ----
    f32x4 acc[2][8];
    #pragma unroll
    for (int i = 0; i < 2; i++)
        #pragma unroll
        for (int c = 0; c < 8; c++) acc[i][c] = (f32x4){0.f, 0.f, 0.f, 0.f};

    const ushort_t* ap0 = a_sh + ((wv * 2 + 0) * 16 + m16) * 136 + q * 8;
    const ushort_t* ap1 = a_sh + ((wv * 2 + 1) * 16 + m16) * 136 + q * 8;
    const ushort_t* wp  = wT + (size_t)m16 * 128 + q * 8;

    #pragma unroll
    for (int k0 = 0; k0 < 128; k0 += 32) {
        bf16x8 a0 = __builtin_bit_cast(bf16x8, *(const u16x8*)(ap0 + k0));
        bf16x8 a1 = __builtin_bit_cast(bf16x8, *(const u16x8*)(ap1 + k0));
        #pragma unroll
        for (int c = 0; c < 8; c++) {
            bf16x8 b = __builtin_bit_cast(bf16x8, *(const u16x8*)(wp + c * (16 * 128) + k0));
            acc[0][c] = __builtin_amdgcn_mfma_f32_16x16x32_bf16(a0, b, acc[0][c], 0, 0, 0);
            acc[1][c] = __builtin_amdgcn_mfma_f32_16x16x32_bf16(a1, b, acc[1][c], 0, 0, 0);
        }
    }

    __syncthreads();   // all MFMA LDS reads done; a_sh now reusable as C tile

    // ---- epilogue: bias, bf16 -> LDS C tile, BN partial sums ----
    float psum[8], psq[8];
    #pragma unroll
    for (int c = 0; c < 8; c++) { psum[c] = 0.f; psq[c] = 0.f; }

    #pragma unroll
    for (int c = 0; c < 8; c++) {
        const int col = c * 16 + m16;
        const float bv = bias[col];
        #pragma unroll
        for (int i = 0; i < 2; i++) {
            const int rb = (wv * 2 + i) * 16 + q * 4;
            #pragma unroll
            for (int r = 0; r < 4; r++) {
                const float v = acc[i][c][r] + bv;
                a_sh[(rb + r) * 136 + col] = f2b(v);
                psum[c] += v; psq[c] += v * v;
            }
        }
    }
    #pragma unroll
    for (int c = 0; c < 8; c++) {
        atomicAdd(&s_sum[c * 16 + m16], psum[c]);
        atomicAdd(&s_sq[c * 16 + m16],  psq[c]);
    }
    __syncthreads();

    // ---- coalesced write-out of h ----
    {
        const int r0 = tid >> 4;
        const int c0 = (tid & 15) * 8;
        #pragma unroll
        for (int it = 0; it < 8; it++) {
            const int rl = r0 + it * 16;
            const u16x8 v = *(const u16x8*)(a_sh + rl * 136 + c0);
            *(u16x8*)(out + (size_t)(base + rl) * 128 + c0) = v;
        }
    }
    if (tid < 128) {
        atomicAdd(&gsum[tid], s_sum[tid]);
        atomicAdd(&gsq[tid],  s_sq[tid]);
    }
}

// ---------------------------------------------------------------------------
// Fold BN stats into per-channel scale/shift (1 block, 128 threads).
// ---------------------------------------------------------------------------
__global__ void bn_stats_kernel(const float* __restrict__ gsum,
                                const float* __restrict__ gsq,
                                const float* __restrict__ gamma,
                                const float* __restrict__ beta,
                                float* __restrict__ bnsc, float* __restrict__ bnsh)
{
    const int c = threadIdx.x;
    const float invN = 1.f / (float)N_PTS;
    const float mean = gsum[c] * invN;
    const float var  = gsq[c] * invN - mean * mean;
    const float sc   = rsqrtf(var + BN_EPS) * gamma[c];
    bnsc[c] = sc;
    bnsh[c] = fmaf(-mean, sc, beta[c]);
}

// ---------------------------------------------------------------------------
// FUSED: BN apply + ReLU (blocks [0,8192)) and p/o copy (blocks [8192,8576)).
// ---------------------------------------------------------------------------
#define BN_BLOCKS ((N_PTS * C_DIM / 8) / 256)   // 8192
#define P_BLOCKS  ((3 * N_PTS / 4) / 256)       // 384

__global__ __launch_bounds__(256) void bn_relu_p_kernel(
    const ushort_t* __restrict__ h, const float* __restrict__ bnsc,
    const float* __restrict__ bnsh, const float* __restrict__ p,
    const int* __restrict__ o, float* __restrict__ out)
{
    const int b = blockIdx.x;
    if (b < BN_BLOCKS) {
        const size_t i = (size_t)b * 256 + threadIdx.x;
        const int c8 = (threadIdx.x * 8) & 127;   // block covers 16 full rows

        const u16x8 hv = *(const u16x8*)(h + i * 8);
        const f32x4 sc0 = *(const f32x4*)(bnsc + c8);
        const f32x4 sc1 = *(const f32x4*)(bnsc + c8 + 4);
        const f32x4 sh0 = *(const f32x4*)(bnsh + c8);
        const f32x4 sh1 = *(const f32x4*)(bnsh + c8 + 4);

        f32x4 o0, o1;
        #pragma unroll
        for (int e = 0; e < 4; e++) {
            o0[e] = fmaxf(fmaf(b2f(hv[e]),     sc0[e], sh0[e]), 0.f);
            o1[e] = fmaxf(fmaf(b2f(hv[4 + e]), sc1[e], sh1[e]), 0.f);
        }
        float* op = out + (size_t)3 * N_PTS + i * 8;
        *(f32x4*)(op)     = o0;
        *(f32x4*)(op + 4) = o1;
    } else {
        const size_t i = (size_t)(b - BN_BLOCKS) * 256 + threadIdx.x;
        *(f32x4*)(out + i * 4) = *(const f32x4*)(p + i * 4);
        if (i == 0)
            out[(size_t)3 * N_PTS + (size_t)N_PTS * C_DIM] = (float)o[0];
    }
}

extern "C" void kernel_launch(void* const* d_in, const int* in_sizes, int n_in,
                              void* d_out, int out_size, void* d_ws, size_t ws_size,
                              hipStream_t stream) {
    const float* p     = (const float*)d_in[0];
    const float* u     = (const float*)d_in[1];
    const int*   o     = (const int*)d_in[2];
    const int*   idx   = (const int*)d_in[3];
    const float* W1    = (const float*)d_in[4];
    const float* b1    = (const float*)d_in[5];
    const float* W2    = (const float*)d_in[6];
    const float* b2    = (const float*)d_in[7];
    const float* gamma = (const float*)d_in[8];
    const float* beta  = (const float*)d_in[9];
    float* out = (float*)d_out;

    char* ws = (char*)d_ws;
    const size_t buf_bytes = (size_t)N_PTS * C_DIM * sizeof(ushort_t);  // 32 MB
    ushort_t* table = (ushort_t*)ws;                       // u_pre, bf16
    ushort_t* h     = (ushort_t*)(ws + buf_bytes);         // pre-BN, bf16
    float*    stats = (float*)(ws + 2 * buf_bytes);
    float* gsum = stats;        // [128]
    float* gsq  = stats + 128;  // [128]
    float* bnsc = stats + 256;  // [128]
    float* bnsh = stats + 384;  // [128]
    ushort_t* wT1 = (ushort_t*)(stats + 512);              // [128*128] bf16
    ushort_t* wT2 = wT1 + 128 * 128;

    hipMemsetAsync(stats, 0, 256 * sizeof(float), stream);

    prep_w_kernel<<<64, 256, 0, stream>>>(W1, W2, wT1, wT2);
    gemm_mfma_kernel<false, false><<<N_PTS / 128, 256, 0, stream>>>(
        u, wT1, b1, table, nullptr, nullptr);
    lap_gemm_kernel<<<N_PTS / 128, 256, 0, stream>>>(
        table, idx, wT2, b2, h, gsum, gsq);
    bn_stats_kernel<<<1, 128, 0, stream>>>(gsum, gsq, gamma, beta, bnsc, bnsh);
    bn_relu_p_kernel<<<BN_BLOCKS + P_BLOCKS, 256, 0, stream>>>(
        h, bnsc, bnsh, p, o, out);
}

// Round 4
// 331.998 us; speedup vs baseline: 1.0123x; 1.0123x over previous
//
#include <hip/hip_runtime.h>

#define N_PTS 131072
#define C_DIM 128
#define NS_K  16
#define BN_EPS 1e-5f

typedef unsigned short ushort_t;
typedef unsigned short u16x8 __attribute__((ext_vector_type(8)));
typedef __bf16 bf16x8 __attribute__((ext_vector_type(8)));
typedef float f32x4 __attribute__((ext_vector_type(4)));

__device__ __forceinline__ ushort_t f2b(float f) {
    unsigned int u = __float_as_uint(f);
    u += 0x7FFFu + ((u >> 16) & 1u);          // round-to-nearest-even
    return (ushort_t)(u >> 16);
}
__device__ __forceinline__ float b2f(ushort_t h) {
    return __uint_as_float((unsigned int)h << 16);
}

// Accumulate relu(neighbor - center) for one 8-channel chunk.
__device__ __forceinline__ void acc8(float* lacc, const float* ctr, u16x8 nv) {
    #pragma unroll
    for (int e = 0; e < 8; e++)
        lacc[e] += fmaxf(b2f(nv[e]) - ctr[e], 0.f);
}

// ---------------------------------------------------------------------------
// Prep: wT[n][k] = bf16(W[k][n]) for both weight matrices (one-shot, 64 KB).
// ---------------------------------------------------------------------------
__global__ __launch_bounds__(256) void prep_w_kernel(
    const float* __restrict__ W1, const float* __restrict__ W2,
    ushort_t* __restrict__ wT1, ushort_t* __restrict__ wT2)
{
    const int t = blockIdx.x * 256 + threadIdx.x;   // 0..16383
    const int n = t & 127;
    const int k = t >> 7;
    wT1[n * 128 + k] = f2b(W1[k * 128 + n]);
    wT2[n * 128 + k] = f2b(W2[k * 128 + n]);
}

// ---------------------------------------------------------------------------
// MFMA GEMM (gemm1) — PROVEN round-0/2 form, fully reverted (w_sh staged,
// no register cap). out_bf16[N,128] = A_f32[N,128] @ W + bias.
// Fragment layouts (validated): A[m=lane&15][k=q*8+j];
// B[k=q*8+j][n=lane&15] from wT[n][k]; C/D col=lane&15, row=q*4+reg.
// ---------------------------------------------------------------------------
template <bool A_BF16, bool STATS>
__global__ __launch_bounds__(256) void gemm_mfma_kernel(
    const void* __restrict__ Aptr, const ushort_t* __restrict__ wT,
    const float* __restrict__ bias, ushort_t* __restrict__ out,
    float* __restrict__ gsum, float* __restrict__ gsq)
{
    __shared__ __align__(16) ushort_t a_sh[128 * 136];   // A tile, then C tile
    __shared__ __align__(16) ushort_t w_sh[128 * 136];   // wT tile [n][k]
    __shared__ float s_sum[128];
    __shared__ float s_sq[128];

    const int tid  = threadIdx.x;
    const int lane = tid & 63;
    const int wv   = tid >> 6;
    const int m16  = lane & 15;
    const int q    = lane >> 4;
    const int base = blockIdx.x * 128;

    if (STATS && tid < 128) { s_sum[tid] = 0.f; s_sq[tid] = 0.f; }

    // ---- stage A tile (128x128, convert f32->bf16 if needed) ----
    {
        const int row  = tid >> 1;
        const int half = (tid & 1) * 64;
        ushort_t* as = a_sh + row * 136 + half;
        if (A_BF16) {
            const ushort_t* ag = (const ushort_t*)Aptr + (size_t)(base + row) * 128 + half;
            #pragma unroll
            for (int j = 0; j < 8; j++)
                *(u16x8*)(as + j * 8) = *(const u16x8*)(ag + j * 8);
        } else {
            const float* ag = (const float*)Aptr + (size_t)(base + row) * 128 + half;
            #pragma unroll
            for (int j = 0; j < 8; j++) {
                f32x4 lo = *(const f32x4*)(ag + j * 8);
                f32x4 hi = *(const f32x4*)(ag + j * 8 + 4);
                u16x8 v;
                v[0] = f2b(lo[0]); v[1] = f2b(lo[1]); v[2] = f2b(lo[2]); v[3] = f2b(lo[3]);
                v[4] = f2b(hi[0]); v[5] = f2b(hi[1]); v[6] = f2b(hi[2]); v[7] = f2b(hi[3]);
                *(u16x8*)(as + j * 8) = v;
            }
        }
    }
    // ---- stage wT tile (bf16, already transposed; vector copy) ----
    {
        const int n    = tid >> 1;
        const int half = (tid & 1) * 64;
        const ushort_t* wg = wT + (size_t)n * 128 + half;
        ushort_t* ws = w_sh + n * 136 + half;
        #pragma unroll
        for (int j = 0; j < 8; j++)
            *(u16x8*)(ws + j * 8) = *(const u16x8*)(wg + j * 8);
    }
    __syncthreads();

    f32x4 acc[2][8];
    #pragma unroll
    for (int i = 0; i < 2; i++)
        #pragma unroll
        for (int c = 0; c < 8; c++) acc[i][c] = (f32x4){0.f, 0.f, 0.f, 0.f};

    const ushort_t* ap0 = a_sh + ((wv * 2 + 0) * 16 + m16) * 136 + q * 8;
    const ushort_t* ap1 = a_sh + ((wv * 2 + 1) * 16 + m16) * 136 + q * 8;
    const ushort_t* wp  = w_sh + m16 * 136 + q * 8;

    #pragma unroll
    for (int k0 = 0; k0 < 128; k0 += 32) {
        bf16x8 a0 = __builtin_bit_cast(bf16x8, *(const u16x8*)(ap0 + k0));
        bf16x8 a1 = __builtin_bit_cast(bf16x8, *(const u16x8*)(ap1 + k0));
        #pragma unroll
        for (int c = 0; c < 8; c++) {
            bf16x8 b = __builtin_bit_cast(bf16x8, *(const u16x8*)(wp + c * (16 * 136) + k0));
            acc[0][c] = __builtin_amdgcn_mfma_f32_16x16x32_bf16(a0, b, acc[0][c], 0, 0, 0);
            acc[1][c] = __builtin_amdgcn_mfma_f32_16x16x32_bf16(a1, b, acc[1][c], 0, 0, 0);
        }
    }

    __syncthreads();   // all MFMA LDS reads done; a_sh now reusable as C tile

    // ---- epilogue: bias, bf16 -> LDS C tile, BN partial sums ----
    float psum[8], psq[8];
    #pragma unroll
    for (int c = 0; c < 8; c++) { psum[c] = 0.f; psq[c] = 0.f; }

    #pragma unroll
    for (int c = 0; c < 8; c++) {
        const int col = c * 16 + m16;
        const float bv = bias[col];
        #pragma unroll
        for (int i = 0; i < 2; i++) {
            const int rb = (wv * 2 + i) * 16 + q * 4;
            #pragma unroll
            for (int r = 0; r < 4; r++) {
                const float v = acc[i][c][r] + bv;
                a_sh[(rb + r) * 136 + col] = f2b(v);
                if (STATS) { psum[c] += v; psq[c] += v * v; }
            }
        }
    }
    if (STATS) {
        #pragma unroll
        for (int c = 0; c < 8; c++) {
            atomicAdd(&s_sum[c * 16 + m16], psum[c]);
            atomicAdd(&s_sq[c * 16 + m16],  psq[c]);
        }
    }
    __syncthreads();

    // ---- coalesced write-out: 16 lanes cover one 256 B row ----
    {
        const int r0 = tid >> 4;            // 0..15
        const int c0 = (tid & 15) * 8;      // 16 B chunk within row
        #pragma unroll
        for (int it = 0; it < 8; it++) {
            const int rl = r0 + it * 16;
            const u16x8 v = *(const u16x8*)(a_sh + rl * 136 + c0);
            *(u16x8*)(out + (size_t)(base + rl) * 128 + c0) = v;
        }
    }
    if (STATS && tid < 128) {
        atomicAdd(&gsum[tid], s_sum[tid]);
        atomicAdd(&gsq[tid],  s_sq[tid]);
    }
}

// ---------------------------------------------------------------------------
// FUSED: laplacian gather -> A tile in LDS -> MFMA gemm2 -> bias + BN stats.
// Round-4 fix: NO index array (named int4s + two groups of 8 named loads,
// peak live regs ~90 < 128 cap -> no scratch spill); no w_sh (B from global
// wT, L2-hot); no s_idx. LDS = 35840 B -> 4 blocks/CU; launch_bounds(256,4)
// -> 16 waves/CU. Accumulation order s0..s15 preserved (bit-identical).
// ---------------------------------------------------------------------------
__global__ __launch_bounds__(256, 4) void lap_gemm_kernel(
    const ushort_t* __restrict__ table, const int* __restrict__ idx,
    const ushort_t* __restrict__ wT, const float* __restrict__ bias,
    ushort_t* __restrict__ out, float* __restrict__ gsum, float* __restrict__ gsq)
{
    __shared__ __align__(16) ushort_t a_sh[128 * 136];   // lap tile, then C tile
    __shared__ float s_sum[128];
    __shared__ float s_sq[128];

    const int tid  = threadIdx.x;
    const int lane = tid & 63;
    const int wv   = tid >> 6;
    const int m16  = lane & 15;
    const int q    = lane >> 4;
    const int base = blockIdx.x * 128;

    if (tid < 128) { s_sum[tid] = 0.f; s_sq[tid] = 0.f; }

    // ---- gather + laplacian directly into a_sh (bf16, identical rounding) ----
    {
        const int pl = tid >> 4;                 // 0..15: point-in-group
        const int c8 = (tid & 15) * 8;           // 16 B channel chunk
        const ushort_t* tc = table + c8;
        #pragma unroll 1
        for (int it = 0; it < 8; it++) {
            const int pp = it * 16 + pl;         // local point 0..127
            const size_t prow = (size_t)(base + pp);

            // KNN indices: named int4s (no array -> no scratch). 16 lanes of
            // this channel group read the same address -> HW-merged, L2-hot.
            const int4* ig = (const int4*)(idx + prow * NS_K);
            const int4 ia = ig[0];
            const int4 ib = ig[1];

            const u16x8 cv = *(const u16x8*)(tc + prow * 128);
            float ctr[8];
            #pragma unroll
            for (int e = 0; e < 8; e++) ctr[e] = b2f(cv[e]);
            float lacc[8];
            #pragma unroll
            for (int e = 0; e < 8; e++) lacc[e] = 0.f;

            // ---- neighbors s0..s7: 8 named loads in flight ----
            const u16x8 n0 = *(const u16x8*)(tc + (size_t)ia.x * 128);
            const u16x8 n1 = *(const u16x8*)(tc + (size_t)ia.y * 128);
            const u16x8 n2 = *(const u16x8*)(tc + (size_t)ia.z * 128);
            const u16x8 n3 = *(const u16x8*)(tc + (size_t)ia.w * 128);
            const u16x8 n4 = *(const u16x8*)(tc + (size_t)ib.x * 128);
            const u16x8 n5 = *(const u16x8*)(tc + (size_t)ib.y * 128);
            const u16x8 n6 = *(const u16x8*)(tc + (size_t)ib.z * 128);
            const u16x8 n7 = *(const u16x8*)(tc + (size_t)ib.w * 128);
            const int4 ic = ig[2];               // prefetch while gathers fly
            const int4 id = ig[3];
            acc8(lacc, ctr, n0); acc8(lacc, ctr, n1);
            acc8(lacc, ctr, n2); acc8(lacc, ctr, n3);
            acc8(lacc, ctr, n4); acc8(lacc, ctr, n5);
            acc8(lacc, ctr, n6); acc8(lacc, ctr, n7);

            // ---- neighbors s8..s15 ----
            const u16x8 m0 = *(const u16x8*)(tc + (size_t)ic.x * 128);
            const u16x8 m1 = *(const u16x8*)(tc + (size_t)ic.y * 128);
            const u16x8 m2 = *(const u16x8*)(tc + (size_t)ic.z * 128);
            const u16x8 m3 = *(const u16x8*)(tc + (size_t)ic.w * 128);
            const u16x8 m4 = *(const u16x8*)(tc + (size_t)id.x * 128);
            const u16x8 m5 = *(const u16x8*)(tc + (size_t)id.y * 128);
            const u16x8 m6 = *(const u16x8*)(tc + (size_t)id.z * 128);
            const u16x8 m7 = *(const u16x8*)(tc + (size_t)id.w * 128);
            acc8(lacc, ctr, m0); acc8(lacc, ctr, m1);
            acc8(lacc, ctr, m2); acc8(lacc, ctr, m3);
            acc8(lacc, ctr, m4); acc8(lacc, ctr, m5);
            acc8(lacc, ctr, m6); acc8(lacc, ctr, m7);

            u16x8 ov;
            #pragma unroll
            for (int e = 0; e < 8; e++) ov[e] = f2b(lacc[e] * (1.f / (float)NS_K));
            *(u16x8*)(a_sh + pp * 136 + c8) = ov;
        }
    }
    __syncthreads();

    // ---- MFMA: h = lap @ W2 (B direct from global wT, L2-resident) ----
    f32x4 acc[2][8];
    #pragma unroll
    for (int i = 0; i < 2; i++)
        #pragma unroll
        for (int c = 0; c < 8; c++) acc[i][c] = (f32x4){0.f, 0.f, 0.f, 0.f};

    const ushort_t* ap0 = a_sh + ((wv * 2 + 0) * 16 + m16) * 136 + q * 8;
    const ushort_t* ap1 = a_sh + ((wv * 2 + 1) * 16 + m16) * 136 + q * 8;
    const ushort_t* wp  = wT + (size_t)m16 * 128 + q * 8;

    #pragma unroll
    for (int k0 = 0; k0 < 128; k0 += 32) {
        bf16x8 a0 = __builtin_bit_cast(bf16x8, *(const u16x8*)(ap0 + k0));
        bf16x8 a1 = __builtin_bit_cast(bf16x8, *(const u16x8*)(ap1 + k0));
        #pragma unroll
        for (int c = 0; c < 8; c++) {
            bf16x8 b = __builtin_bit_cast(bf16x8, *(const u16x8*)(wp + c * (16 * 128) + k0));
            acc[0][c] = __builtin_amdgcn_mfma_f32_16x16x32_bf16(a0, b, acc[0][c], 0, 0, 0);
            acc[1][c] = __builtin_amdgcn_mfma_f32_16x16x32_bf16(a1, b, acc[1][c], 0, 0, 0);
        }
    }

    __syncthreads();   // all MFMA LDS reads done; a_sh now reusable as C tile

    // ---- epilogue: bias, bf16 -> LDS C tile, BN partial sums ----
    float psum[8], psq[8];
    #pragma unroll
    for (int c = 0; c < 8; c++) { psum[c] = 0.f; psq[c] = 0.f; }

    #pragma unroll
    for (int c = 0; c < 8; c++) {
        const int col = c * 16 + m16;
        const float bv = bias[col];
        #pragma unroll
        for (int i = 0; i < 2; i++) {
            const int rb = (wv * 2 + i) * 16 + q * 4;
            #pragma unroll
            for (int r = 0; r < 4; r++) {
                const float v = acc[i][c][r] + bv;
                a_sh[(rb + r) * 136 + col] = f2b(v);
                psum[c] += v; psq[c] += v * v;
            }
        }
    }
    #pragma unroll
    for (int c = 0; c < 8; c++) {
        atomicAdd(&s_sum[c * 16 + m16], psum[c]);
        atomicAdd(&s_sq[c * 16 + m16],  psq[c]);
    }
    __syncthreads();

    // ---- coalesced write-out of h ----
    {
        const int r0 = tid >> 4;
        const int c0 = (tid & 15) * 8;
        #pragma unroll
        for (int it = 0; it < 8; it++) {
            const int rl = r0 + it * 16;
            const u16x8 v = *(const u16x8*)(a_sh + rl * 136 + c0);
            *(u16x8*)(out + (size_t)(base + rl) * 128 + c0) = v;
        }
    }
    if (tid < 128) {
        atomicAdd(&gsum[tid], s_sum[tid]);
        atomicAdd(&gsq[tid],  s_sq[tid]);
    }
}

// ---------------------------------------------------------------------------
// Fold BN stats into per-channel scale/shift (1 block, 128 threads).
// ---------------------------------------------------------------------------
__global__ void bn_stats_kernel(const float* __restrict__ gsum,
                                const float* __restrict__ gsq,
                                const float* __restrict__ gamma,
                                const float* __restrict__ beta,
                                float* __restrict__ bnsc, float* __restrict__ bnsh)
{
    const int c = threadIdx.x;
    const float invN = 1.f / (float)N_PTS;
    const float mean = gsum[c] * invN;
    const float var  = gsq[c] * invN - mean * mean;
    const float sc   = rsqrtf(var + BN_EPS) * gamma[c];
    bnsc[c] = sc;
    bnsh[c] = fmaf(-mean, sc, beta[c]);
}

// ---------------------------------------------------------------------------
// FUSED: BN apply + ReLU (blocks [0,8192)) and p/o copy (blocks [8192,8576)).
// ---------------------------------------------------------------------------
#define BN_BLOCKS ((N_PTS * C_DIM / 8) / 256)   // 8192
#define P_BLOCKS  ((3 * N_PTS / 4) / 256)       // 384

__global__ __launch_bounds__(256) void bn_relu_p_kernel(
    const ushort_t* __restrict__ h, const float* __restrict__ bnsc,
    const float* __restrict__ bnsh, const float* __restrict__ p,
    const int* __restrict__ o, float* __restrict__ out)
{
    const int b = blockIdx.x;
    if (b < BN_BLOCKS) {
        const size_t i = (size_t)b * 256 + threadIdx.x;
        const int c8 = (threadIdx.x * 8) & 127;   // block covers 16 full rows

        const u16x8 hv = *(const u16x8*)(h + i * 8);
        const f32x4 sc0 = *(const f32x4*)(bnsc + c8);
        const f32x4 sc1 = *(const f32x4*)(bnsc + c8 + 4);
        const f32x4 sh0 = *(const f32x4*)(bnsh + c8);
        const f32x4 sh1 = *(const f32x4*)(bnsh + c8 + 4);

        f32x4 o0, o1;
        #pragma unroll
        for (int e = 0; e < 4; e++) {
            o0[e] = fmaxf(fmaf(b2f(hv[e]),     sc0[e], sh0[e]), 0.f);
            o1[e] = fmaxf(fmaf(b2f(hv[4 + e]), sc1[e], sh1[e]), 0.f);
        }
        float* op = out + (size_t)3 * N_PTS + i * 8;
        *(f32x4*)(op)     = o0;
        *(f32x4*)(op + 4) = o1;
    } else {
        const size_t i = (size_t)(b - BN_BLOCKS) * 256 + threadIdx.x;
        *(f32x4*)(out + i * 4) = *(const f32x4*)(p + i * 4);
        if (i == 0)
            out[(size_t)3 * N_PTS + (size_t)N_PTS * C_DIM] = (float)o[0];
    }
}

extern "C" void kernel_launch(void* const* d_in, const int* in_sizes, int n_in,
                              void* d_out, int out_size, void* d_ws, size_t ws_size,
                              hipStream_t stream) {
    const float* p     = (const float*)d_in[0];
    const float* u     = (const float*)d_in[1];
    const int*   o     = (const int*)d_in[2];
    const int*   idx   = (const int*)d_in[3];
    const float* W1    = (const float*)d_in[4];
    const float* b1    = (const float*)d_in[5];
    const float* W2    = (const float*)d_in[6];
    const float* b2    = (const float*)d_in[7];
    const float* gamma = (const float*)d_in[8];
    const float* beta  = (const float*)d_in[9];
    float* out = (float*)d_out;

    char* ws = (char*)d_ws;
    const size_t buf_bytes = (size_t)N_PTS * C_DIM * sizeof(ushort_t);  // 32 MB
    ushort_t* table = (ushort_t*)ws;                       // u_pre, bf16
    ushort_t* h     = (ushort_t*)(ws + buf_bytes);         // pre-BN, bf16
    float*    stats = (float*)(ws + 2 * buf_bytes);
    float* gsum = stats;        // [128]
    float* gsq  = stats + 128;  // [128]
    float* bnsc = stats + 256;  // [128]
    float* bnsh = stats + 384;  // [128]
    ushort_t* wT1 = (ushort_t*)(stats + 512);              // [128*128] bf16
    ushort_t* wT2 = wT1 + 128 * 128;

    hipMemsetAsync(stats, 0, 256 * sizeof(float), stream);

    prep_w_kernel<<<64, 256, 0, stream>>>(W1, W2, wT1, wT2);
    gemm_mfma_kernel<false, false><<<N_PTS / 128, 256, 0, stream>>>(
        u, wT1, b1, table, nullptr, nullptr);
    lap_gemm_kernel<<<N_PTS / 128, 256, 0, stream>>>(
        table, idx, wT2, b2, h, gsum, gsq);
    bn_stats_kernel<<<1, 128, 0, stream>>>(gsum, gsq, gamma, beta, bnsc, bnsh);
    bn_relu_p_kernel<<<BN_BLOCKS + P_BLOCKS, 256, 0, stream>>>(
        h, bnsc, bnsh, p, o, out);
}

// Round 5
// 331.435 us; speedup vs baseline: 1.0140x; 1.0017x over previous
//
#include <hip/hip_runtime.h>

#define N_PTS 131072
#define C_DIM 128
#define NS_K  16
#define BN_EPS 1e-5f

typedef unsigned short ushort_t;
typedef unsigned short u16x8 __attribute__((ext_vector_type(8)));
typedef __bf16 bf16x8 __attribute__((ext_vector_type(8)));
typedef float f32x4 __attribute__((ext_vector_type(4)));

__device__ __forceinline__ ushort_t f2b(float f) {
    unsigned int u = __float_as_uint(f);
    u += 0x7FFFu + ((u >> 16) & 1u);          // round-to-nearest-even
    return (ushort_t)(u >> 16);
}
__device__ __forceinline__ float b2f(ushort_t h) {
    return __uint_as_float((unsigned int)h << 16);
}

// Accumulate relu(neighbor - center) for one 8-channel chunk.
__device__ __forceinline__ void acc8(float* lacc, const float* ctr, u16x8 nv) {
    #pragma unroll
    for (int e = 0; e < 8; e++)
        lacc[e] += fmaxf(b2f(nv[e]) - ctr[e], 0.f);
}

// ---------------------------------------------------------------------------
// Prep: wT[n][k] = bf16(W[k][n]) for both weight matrices (one-shot, 64 KB).
// ---------------------------------------------------------------------------
__global__ __launch_bounds__(256) void prep_w_kernel(
    const float* __restrict__ W1, const float* __restrict__ W2,
    ushort_t* __restrict__ wT1, ushort_t* __restrict__ wT2)
{
    const int t = blockIdx.x * 256 + threadIdx.x;   // 0..16383
    const int n = t & 127;
    const int k = t >> 7;
    wT1[n * 128 + k] = f2b(W1[k * 128 + n]);
    wT2[n * 128 + k] = f2b(W2[k * 128 + n]);
}

// ---------------------------------------------------------------------------
// MFMA GEMM (gemm1) — PROVEN round-0/2 form (w_sh staged, no register cap).
// out_bf16[N,128] = A_f32[N,128] @ W + bias.
// Fragment layouts (validated): A[m=lane&15][k=q*8+j];
// B[k=q*8+j][n=lane&15] from wT[n][k]; C/D col=lane&15, row=q*4+reg.
// ---------------------------------------------------------------------------
template <bool A_BF16, bool STATS>
__global__ __launch_bounds__(256) void gemm_mfma_kernel(
    const void* __restrict__ Aptr, const ushort_t* __restrict__ wT,
    const float* __restrict__ bias, ushort_t* __restrict__ out,
    float* __restrict__ gsum, float* __restrict__ gsq)
{
    __shared__ __align__(16) ushort_t a_sh[128 * 136];   // A tile, then C tile
    __shared__ __align__(16) ushort_t w_sh[128 * 136];   // wT tile [n][k]
    __shared__ float s_sum[128];
    __shared__ float s_sq[128];

    const int tid  = threadIdx.x;
    const int lane = tid & 63;
    const int wv   = tid >> 6;
    const int m16  = lane & 15;
    const int q    = lane >> 4;
    const int base = blockIdx.x * 128;

    if (STATS && tid < 128) { s_sum[tid] = 0.f; s_sq[tid] = 0.f; }

    // ---- stage A tile (128x128, convert f32->bf16 if needed) ----
    {
        const int row  = tid >> 1;
        const int half = (tid & 1) * 64;
        ushort_t* as = a_sh + row * 136 + half;
        if (A_BF16) {
            const ushort_t* ag = (const ushort_t*)Aptr + (size_t)(base + row) * 128 + half;
            #pragma unroll
            for (int j = 0; j < 8; j++)
                *(u16x8*)(as + j * 8) = *(const u16x8*)(ag + j * 8);
        } else {
            const float* ag = (const float*)Aptr + (size_t)(base + row) * 128 + half;
            #pragma unroll
            for (int j = 0; j < 8; j++) {
                f32x4 lo = *(const f32x4*)(ag + j * 8);
                f32x4 hi = *(const f32x4*)(ag + j * 8 + 4);
                u16x8 v;
                v[0] = f2b(lo[0]); v[1] = f2b(lo[1]); v[2] = f2b(lo[2]); v[3] = f2b(lo[3]);
                v[4] = f2b(hi[0]); v[5] = f2b(hi[1]); v[6] = f2b(hi[2]); v[7] = f2b(hi[3]);
                *(u16x8*)(as + j * 8) = v;
            }
        }
    }
    // ---- stage wT tile (bf16, already transposed; vector copy) ----
    {
        const int n    = tid >> 1;
        const int half = (tid & 1) * 64;
        const ushort_t* wg = wT + (size_t)n * 128 + half;
        ushort_t* ws = w_sh + n * 136 + half;
        #pragma unroll
        for (int j = 0; j < 8; j++)
            *(u16x8*)(ws + j * 8) = *(const u16x8*)(wg + j * 8);
    }
    __syncthreads();

    f32x4 acc[2][8];
    #pragma unroll
    for (int i = 0; i < 2; i++)
        #pragma unroll
        for (int c = 0; c < 8; c++) acc[i][c] = (f32x4){0.f, 0.f, 0.f, 0.f};

    const ushort_t* ap0 = a_sh + ((wv * 2 + 0) * 16 + m16) * 136 + q * 8;
    const ushort_t* ap1 = a_sh + ((wv * 2 + 1) * 16 + m16) * 136 + q * 8;
    const ushort_t* wp  = w_sh + m16 * 136 + q * 8;

    #pragma unroll
    for (int k0 = 0; k0 < 128; k0 += 32) {
        bf16x8 a0 = __builtin_bit_cast(bf16x8, *(const u16x8*)(ap0 + k0));
        bf16x8 a1 = __builtin_bit_cast(bf16x8, *(const u16x8*)(ap1 + k0));
        #pragma unroll
        for (int c = 0; c < 8; c++) {
            bf16x8 b = __builtin_bit_cast(bf16x8, *(const u16x8*)(wp + c * (16 * 136) + k0));
            acc[0][c] = __builtin_amdgcn_mfma_f32_16x16x32_bf16(a0, b, acc[0][c], 0, 0, 0);
            acc[1][c] = __builtin_amdgcn_mfma_f32_16x16x32_bf16(a1, b, acc[1][c], 0, 0, 0);
        }
    }

    __syncthreads();   // all MFMA LDS reads done; a_sh now reusable as C tile

    // ---- epilogue: bias, bf16 -> LDS C tile, BN partial sums ----
    float psum[8], psq[8];
    #pragma unroll
    for (int c = 0; c < 8; c++) { psum[c] = 0.f; psq[c] = 0.f; }

    #pragma unroll
    for (int c = 0; c < 8; c++) {
        const int col = c * 16 + m16;
        const float bv = bias[col];
        #pragma unroll
        for (int i = 0; i < 2; i++) {
            const int rb = (wv * 2 + i) * 16 + q * 4;
            #pragma unroll
            for (int r = 0; r < 4; r++) {
                const float v = acc[i][c][r] + bv;
                a_sh[(rb + r) * 136 + col] = f2b(v);
                if (STATS) { psum[c] += v; psq[c] += v * v; }
            }
        }
    }
    if (STATS) {
        #pragma unroll
        for (int c = 0; c < 8; c++) {
            atomicAdd(&s_sum[c * 16 + m16], psum[c]);
            atomicAdd(&s_sq[c * 16 + m16],  psq[c]);
        }
    }
    __syncthreads();

    // ---- coalesced write-out: 16 lanes cover one 256 B row ----
    {
        const int r0 = tid >> 4;            // 0..15
        const int c0 = (tid & 15) * 8;      // 16 B chunk within row
        #pragma unroll
        for (int it = 0; it < 8; it++) {
            const int rl = r0 + it * 16;
            const u16x8 v = *(const u16x8*)(a_sh + rl * 136 + c0);
            *(u16x8*)(out + (size_t)(base + rl) * 128 + c0) = v;
        }
    }
    if (STATS && tid < 128) {
        atomicAdd(&gsum[tid], s_sum[tid]);
        atomicAdd(&gsq[tid],  s_sq[tid]);
    }
}

// ---------------------------------------------------------------------------
// FUSED: laplacian gather -> A tile in LDS -> MFMA gemm2 -> bias + BN stats.
// Round-5 fix: amdgpu_waves_per_eu(4,4) pins the occupancy TARGET at exactly
// 4 waves/EU (16 waves/CU). Round-3/4's launch_bounds(256,4) only set a MIN;
// LLVM's memory-bound heuristic targeted 8 waves/EU -> 64 VGPRs -> ~130 MB
// scratch spill (observed: VGPR_Count=64, WRITE_SIZE 34->167 MB). With the
// max pinned, allocator gets the full 128-reg budget. Gather depth reduced
// to 4 in-flight loads (peak live ~60 regs; 4-deep x 16 waves = ample MLP).
// LDS = 35840 B -> 4 blocks/CU. Accumulation order s0..s15 preserved.
// ---------------------------------------------------------------------------
__attribute__((amdgpu_waves_per_eu(4, 4)))
__global__ __launch_bounds__(256) void lap_gemm_kernel(
    const ushort_t* __restrict__ table, const int* __restrict__ idx,
    const ushort_t* __restrict__ wT, const float* __restrict__ bias,
    ushort_t* __restrict__ out, float* __restrict__ gsum, float* __restrict__ gsq)
{
    __shared__ __align__(16) ushort_t a_sh[128 * 136];   // lap tile, then C tile
    __shared__ float s_sum[128];
    __shared__ float s_sq[128];

    const int tid  = threadIdx.x;
    const int lane = tid & 63;
    const int wv   = tid >> 6;
    const int m16  = lane & 15;
    const int q    = lane >> 4;
    const int base = blockIdx.x * 128;

    if (tid < 128) { s_sum[tid] = 0.f; s_sq[tid] = 0.f; }

    // ---- gather + laplacian directly into a_sh (bf16, identical rounding) ----
    {
        const int pl = tid >> 4;                 // 0..15: point-in-group
        const int c8 = (tid & 15) * 8;           // 16 B channel chunk
        const ushort_t* tc = table + c8;
        #pragma unroll 1
        for (int it = 0; it < 8; it++) {
            const int pp = it * 16 + pl;         // local point 0..127
            const size_t prow = (size_t)(base + pp);

            // KNN indices: named int4s (no array -> no scratch). 16 lanes of
            // this channel group read the same address -> HW-merged, L2-hot.
            const int4* ig = (const int4*)(idx + prow * NS_K);
            const int4 ia = ig[0];

            const u16x8 cv = *(const u16x8*)(tc + prow * 128);
            float ctr[8];
            #pragma unroll
            for (int e = 0; e < 8; e++) ctr[e] = b2f(cv[e]);
            float lacc[8];
            #pragma unroll
            for (int e = 0; e < 8; e++) lacc[e] = 0.f;

            // ---- s0..s3 in flight; prefetch next index quad meanwhile ----
            const u16x8 n0 = *(const u16x8*)(tc + (size_t)ia.x * 128);
            const u16x8 n1 = *(const u16x8*)(tc + (size_t)ia.y * 128);
            const u16x8 n2 = *(const u16x8*)(tc + (size_t)ia.z * 128);
            const u16x8 n3 = *(const u16x8*)(tc + (size_t)ia.w * 128);
            const int4 ib = ig[1];
            acc8(lacc, ctr, n0); acc8(lacc, ctr, n1);
            acc8(lacc, ctr, n2); acc8(lacc, ctr, n3);

            // ---- s4..s7 ----
            const u16x8 n4 = *(const u16x8*)(tc + (size_t)ib.x * 128);
            const u16x8 n5 = *(const u16x8*)(tc + (size_t)ib.y * 128);
            const u16x8 n6 = *(const u16x8*)(tc + (size_t)ib.z * 128);
            const u16x8 n7 = *(const u16x8*)(tc + (size_t)ib.w * 128);
            const int4 ic = ig[2];
            acc8(lacc, ctr, n4); acc8(lacc, ctr, n5);
            acc8(lacc, ctr, n6); acc8(lacc, ctr, n7);

            // ---- s8..s11 ----
            const u16x8 m0 = *(const u16x8*)(tc + (size_t)ic.x * 128);
            const u16x8 m1 = *(const u16x8*)(tc + (size_t)ic.y * 128);
            const u16x8 m2 = *(const u16x8*)(tc + (size_t)ic.z * 128);
            const u16x8 m3 = *(const u16x8*)(tc + (size_t)ic.w * 128);
            const int4 id = ig[3];
            acc8(lacc, ctr, m0); acc8(lacc, ctr, m1);
            acc8(lacc, ctr, m2); acc8(lacc, ctr, m3);

            // ---- s12..s15 ----
            const u16x8 m4 = *(const u16x8*)(tc + (size_t)id.x * 128);
            const u16x8 m5 = *(const u16x8*)(tc + (size_t)id.y * 128);
            const u16x8 m6 = *(const u16x8*)(tc + (size_t)id.z * 128);
            const u16x8 m7 = *(const u16x8*)(tc + (size_t)id.w * 128);
            acc8(lacc, ctr, m4); acc8(lacc, ctr, m5);
            acc8(lacc, ctr, m6); acc8(lacc, ctr, m7);

            u16x8 ov;
            #pragma unroll
            for (int e = 0; e < 8; e++) ov[e] = f2b(lacc[e] * (1.f / (float)NS_K));
            *(u16x8*)(a_sh + pp * 136 + c8) = ov;
        }
    }
    __syncthreads();

    // ---- MFMA: h = lap @ W2 (B direct from global wT, L2-resident) ----
    f32x4 acc[2][8];
    #pragma unroll
    for (int i = 0; i < 2; i++)
        #pragma unroll
        for (int c = 0; c < 8; c++) acc[i][c] = (f32x4){0.f, 0.f, 0.f, 0.f};

    const ushort_t* ap0 = a_sh + ((wv * 2 + 0) * 16 + m16) * 136 + q * 8;
    const ushort_t* ap1 = a_sh + ((wv * 2 + 1) * 16 + m16) * 136 + q * 8;
    const ushort_t* wp  = wT + (size_t)m16 * 128 + q * 8;

    #pragma unroll
    for (int k0 = 0; k0 < 128; k0 += 32) {
        bf16x8 a0 = __builtin_bit_cast(bf16x8, *(const u16x8*)(ap0 + k0));
        bf16x8 a1 = __builtin_bit_cast(bf16x8, *(const u16x8*)(ap1 + k0));
        #pragma unroll
        for (int c = 0; c < 8; c++) {
            bf16x8 b = __builtin_bit_cast(bf16x8, *(const u16x8*)(wp + c * (16 * 128) + k0));
            acc[0][c] = __builtin_amdgcn_mfma_f32_16x16x32_bf16(a0, b, acc[0][c], 0, 0, 0);
            acc[1][c] = __builtin_amdgcn_mfma_f32_16x16x32_bf16(a1, b, acc[1][c], 0, 0, 0);
        }
    }

    __syncthreads();   // all MFMA LDS reads done; a_sh now reusable as C tile

    // ---- epilogue: bias, bf16 -> LDS C tile, BN partial sums ----
    float psum[8], psq[8];
    #pragma unroll
    for (int c = 0; c < 8; c++) { psum[c] = 0.f; psq[c] = 0.f; }

    #pragma unroll
    for (int c = 0; c < 8; c++) {
        const int col = c * 16 + m16;
        const float bv = bias[col];
        #pragma unroll
        for (int i = 0; i < 2; i++) {
            const int rb = (wv * 2 + i) * 16 + q * 4;
            #pragma unroll
            for (int r = 0; r < 4; r++) {
                const float v = acc[i][c][r] + bv;
                a_sh[(rb + r) * 136 + col] = f2b(v);
                psum[c] += v; psq[c] += v * v;
            }
        }
    }
    #pragma unroll
    for (int c = 0; c < 8; c++) {
        atomicAdd(&s_sum[c * 16 + m16], psum[c]);
        atomicAdd(&s_sq[c * 16 + m16],  psq[c]);
    }
    __syncthreads();

    // ---- coalesced write-out of h ----
    {
        const int r0 = tid >> 4;
        const int c0 = (tid & 15) * 8;
        #pragma unroll
        for (int it = 0; it < 8; it++) {
            const int rl = r0 + it * 16;
            const u16x8 v = *(const u16x8*)(a_sh + rl * 136 + c0);
            *(u16x8*)(out + (size_t)(base + rl) * 128 + c0) = v;
        }
    }
    if (tid < 128) {
        atomicAdd(&gsum[tid], s_sum[tid]);
        atomicAdd(&gsq[tid],  s_sq[tid]);
    }
}

// ---------------------------------------------------------------------------
// Fold BN stats into per-channel scale/shift (1 block, 128 threads).
// ---------------------------------------------------------------------------
__global__ void bn_stats_kernel(const float* __restrict__ gsum,
                                const float* __restrict__ gsq,
                                const float* __restrict__ gamma,
                                const float* __restrict__ beta,
                                float* __restrict__ bnsc, float* __restrict__ bnsh)
{
    const int c = threadIdx.x;
    const float invN = 1.f / (float)N_PTS;
    const float mean = gsum[c] * invN;
    const float var  = gsq[c] * invN - mean * mean;
    const float sc   = rsqrtf(var + BN_EPS) * gamma[c];
    bnsc[c] = sc;
    bnsh[c] = fmaf(-mean, sc, beta[c]);
}

// ---------------------------------------------------------------------------
// FUSED: BN apply + ReLU (blocks [0,8192)) and p/o copy (blocks [8192,8576)).
// ---------------------------------------------------------------------------
#define BN_BLOCKS ((N_PTS * C_DIM / 8) / 256)   // 8192
#define P_BLOCKS  ((3 * N_PTS / 4) / 256)       // 384

__global__ __launch_bounds__(256) void bn_relu_p_kernel(
    const ushort_t* __restrict__ h, const float* __restrict__ bnsc,
    const float* __restrict__ bnsh, const float* __restrict__ p,
    const int* __restrict__ o, float* __restrict__ out)
{
    const int b = blockIdx.x;
    if (b < BN_BLOCKS) {
        const size_t i = (size_t)b * 256 + threadIdx.x;
        const int c8 = (threadIdx.x * 8) & 127;   // block covers 16 full rows

        const u16x8 hv = *(const u16x8*)(h + i * 8);
        const f32x4 sc0 = *(const f32x4*)(bnsc + c8);
        const f32x4 sc1 = *(const f32x4*)(bnsc + c8 + 4);
        const f32x4 sh0 = *(const f32x4*)(bnsh + c8);
        const f32x4 sh1 = *(const f32x4*)(bnsh + c8 + 4);

        f32x4 o0, o1;
        #pragma unroll
        for (int e = 0; e < 4; e++) {
            o0[e] = fmaxf(fmaf(b2f(hv[e]),     sc0[e], sh0[e]), 0.f);
            o1[e] = fmaxf(fmaf(b2f(hv[4 + e]), sc1[e], sh1[e]), 0.f);
        }
        float* op = out + (size_t)3 * N_PTS + i * 8;
        *(f32x4*)(op)     = o0;
        *(f32x4*)(op + 4) = o1;
    } else {
        const size_t i = (size_t)(b - BN_BLOCKS) * 256 + threadIdx.x;
        *(f32x4*)(out + i * 4) = *(const f32x4*)(p + i * 4);
        if (i == 0)
            out[(size_t)3 * N_PTS + (size_t)N_PTS * C_DIM] = (float)o[0];
    }
}

extern "C" void kernel_launch(void* const* d_in, const int* in_sizes, int n_in,
                              void* d_out, int out_size, void* d_ws, size_t ws_size,
                              hipStream_t stream) {
    const float* p     = (const float*)d_in[0];
    const float* u     = (const float*)d_in[1];
    const int*   o     = (const int*)d_in[2];
    const int*   idx   = (const int*)d_in[3];
    const float* W1    = (const float*)d_in[4];
    const float* b1    = (const float*)d_in[5];
    const float* W2    = (const float*)d_in[6];
    const float* b2    = (const float*)d_in[7];
    const float* gamma = (const float*)d_in[8];
    const float* beta  = (const float*)d_in[9];
    float* out = (float*)d_out;

    char* ws = (char*)d_ws;
    const size_t buf_bytes = (size_t)N_PTS * C_DIM * sizeof(ushort_t);  // 32 MB
    ushort_t* table = (ushort_t*)ws;                       // u_pre, bf16
    ushort_t* h     = (ushort_t*)(ws + buf_bytes);         // pre-BN, bf16
    float*    stats = (float*)(ws + 2 * buf_bytes);
    float* gsum = stats;        // [128]
    float* gsq  = stats + 128;  // [128]
    float* bnsc = stats + 256;  // [128]
    float* bnsh = stats + 384;  // [128]
    ushort_t* wT1 = (ushort_t*)(stats + 512);              // [128*128] bf16
    ushort_t* wT2 = wT1 + 128 * 128;

    hipMemsetAsync(stats, 0, 256 * sizeof(float), stream);

    prep_w_kernel<<<64, 256, 0, stream>>>(W1, W2, wT1, wT2);
    gemm_mfma_kernel<false, false><<<N_PTS / 128, 256, 0, stream>>>(
        u, wT1, b1, table, nullptr, nullptr);
    lap_gemm_kernel<<<N_PTS / 128, 256, 0, stream>>>(
        table, idx, wT2, b2, h, gsum, gsq);
    bn_stats_kernel<<<1, 128, 0, stream>>>(gsum, gsq, gamma, beta, bnsc, bnsh);
    bn_relu_p_kernel<<<BN_BLOCKS + P_BLOCKS, 256, 0, stream>>>(
        h, bnsc, bnsh, p, o, out);
}

// Round 6
// 273.949 us; speedup vs baseline: 1.2268x; 1.2098x over previous
//
#include <hip/hip_runtime.h>

#define N_PTS 131072
#define C_DIM 128
#define NS_K  16
#define BN_EPS 1e-5f

typedef unsigned short ushort_t;
typedef unsigned short u16x8 __attribute__((ext_vector_type(8)));
typedef __bf16 bf16x8 __attribute__((ext_vector_type(8)));
typedef float f32x4 __attribute__((ext_vector_type(4)));

__device__ __forceinline__ ushort_t f2b(float f) {
    unsigned int u = __float_as_uint(f);
    u += 0x7FFFu + ((u >> 16) & 1u);          // round-to-nearest-even
    return (ushort_t)(u >> 16);
}
__device__ __forceinline__ float b2f(ushort_t h) {
    return __uint_as_float((unsigned int)h << 16);
}

// Accumulate relu(neighbor - center) for one 8-channel chunk.
__device__ __forceinline__ void acc8(float* lacc, const float* ctr, u16x8 nv) {
    #pragma unroll
    for (int e = 0; e < 8; e++)
        lacc[e] += fmaxf(b2f(nv[e]) - ctr[e], 0.f);
}

// ---------------------------------------------------------------------------
// Prep: wT[n][k] = bf16(W[k][n]) for both weight matrices (one-shot, 64 KB).
// ---------------------------------------------------------------------------
__global__ __launch_bounds__(256) void prep_w_kernel(
    const float* __restrict__ W1, const float* __restrict__ W2,
    ushort_t* __restrict__ wT1, ushort_t* __restrict__ wT2)
{
    const int t = blockIdx.x * 256 + threadIdx.x;   // 0..16383
    const int n = t & 127;
    const int k = t >> 7;
    wT1[n * 128 + k] = f2b(W1[k * 128 + n]);
    wT2[n * 128 + k] = f2b(W2[k * 128 + n]);
}

// ---------------------------------------------------------------------------
// MFMA GEMM (gemm1) — PROVEN round-0/2 form (w_sh staged, no register cap).
// out_bf16[N,128] = A_f32[N,128] @ W + bias.
// Fragment layouts (validated): A[m=lane&15][k=q*8+j];
// B[k=q*8+j][n=lane&15] from wT[n][k]; C/D col=lane&15, row=q*4+reg.
// ---------------------------------------------------------------------------
template <bool A_BF16, bool STATS>
__global__ __launch_bounds__(256) void gemm_mfma_kernel(
    const void* __restrict__ Aptr, const ushort_t* __restrict__ wT,
    const float* __restrict__ bias, ushort_t* __restrict__ out,
    float* __restrict__ gsum, float* __restrict__ gsq)
{
    __shared__ __align__(16) ushort_t a_sh[128 * 136];   // A tile, then C tile
    __shared__ __align__(16) ushort_t w_sh[128 * 136];   // wT tile [n][k]
    __shared__ float s_sum[128];
    __shared__ float s_sq[128];

    const int tid  = threadIdx.x;
    const int lane = tid & 63;
    const int wv   = tid >> 6;
    const int m16  = lane & 15;
    const int q    = lane >> 4;
    const int base = blockIdx.x * 128;

    if (STATS && tid < 128) { s_sum[tid] = 0.f; s_sq[tid] = 0.f; }

    // ---- stage A tile (128x128, convert f32->bf16 if needed) ----
    {
        const int row  = tid >> 1;
        const int half = (tid & 1) * 64;
        ushort_t* as = a_sh + row * 136 + half;
        if (A_BF16) {
            const ushort_t* ag = (const ushort_t*)Aptr + (size_t)(base + row) * 128 + half;
            #pragma unroll
            for (int j = 0; j < 8; j++)
                *(u16x8*)(as + j * 8) = *(const u16x8*)(ag + j * 8);
        } else {
            const float* ag = (const float*)Aptr + (size_t)(base + row) * 128 + half;
            #pragma unroll
            for (int j = 0; j < 8; j++) {
                f32x4 lo = *(const f32x4*)(ag + j * 8);
                f32x4 hi = *(const f32x4*)(ag + j * 8 + 4);
                u16x8 v;
                v[0] = f2b(lo[0]); v[1] = f2b(lo[1]); v[2] = f2b(lo[2]); v[3] = f2b(lo[3]);
                v[4] = f2b(hi[0]); v[5] = f2b(hi[1]); v[6] = f2b(hi[2]); v[7] = f2b(hi[3]);
                *(u16x8*)(as + j * 8) = v;
            }
        }
    }
    // ---- stage wT tile (bf16, already transposed; vector copy) ----
    {
        const int n    = tid >> 1;
        const int half = (tid & 1) * 64;
        const ushort_t* wg = wT + (size_t)n * 128 + half;
        ushort_t* ws = w_sh + n * 136 + half;
        #pragma unroll
        for (int j = 0; j < 8; j++)
            *(u16x8*)(ws + j * 8) = *(const u16x8*)(wg + j * 8);
    }
    __syncthreads();

    f32x4 acc[2][8];
    #pragma unroll
    for (int i = 0; i < 2; i++)
        #pragma unroll
        for (int c = 0; c < 8; c++) acc[i][c] = (f32x4){0.f, 0.f, 0.f, 0.f};

    const ushort_t* ap0 = a_sh + ((wv * 2 + 0) * 16 + m16) * 136 + q * 8;
    const ushort_t* ap1 = a_sh + ((wv * 2 + 1) * 16 + m16) * 136 + q * 8;
    const ushort_t* wp  = w_sh + m16 * 136 + q * 8;

    #pragma unroll
    for (int k0 = 0; k0 < 128; k0 += 32) {
        bf16x8 a0 = __builtin_bit_cast(bf16x8, *(const u16x8*)(ap0 + k0));
        bf16x8 a1 = __builtin_bit_cast(bf16x8, *(const u16x8*)(ap1 + k0));
        #pragma unroll
        for (int c = 0; c < 8; c++) {
            bf16x8 b = __builtin_bit_cast(bf16x8, *(const u16x8*)(wp + c * (16 * 136) + k0));
            acc[0][c] = __builtin_amdgcn_mfma_f32_16x16x32_bf16(a0, b, acc[0][c], 0, 0, 0);
            acc[1][c] = __builtin_amdgcn_mfma_f32_16x16x32_bf16(a1, b, acc[1][c], 0, 0, 0);
        }
    }

    __syncthreads();   // all MFMA LDS reads done; a_sh now reusable as C tile

    // ---- epilogue: bias, bf16 -> LDS C tile, BN partial sums ----
    float psum[8], psq[8];
    #pragma unroll
    for (int c = 0; c < 8; c++) { psum[c] = 0.f; psq[c] = 0.f; }

    #pragma unroll
    for (int c = 0; c < 8; c++) {
        const int col = c * 16 + m16;
        const float bv = bias[col];
        #pragma unroll
        for (int i = 0; i < 2; i++) {
            const int rb = (wv * 2 + i) * 16 + q * 4;
            #pragma unroll
            for (int r = 0; r < 4; r++) {
                const float v = acc[i][c][r] + bv;
                a_sh[(rb + r) * 136 + col] = f2b(v);
                if (STATS) { psum[c] += v; psq[c] += v * v; }
            }
        }
    }
    if (STATS) {
        #pragma unroll
        for (int c = 0; c < 8; c++) {
            atomicAdd(&s_sum[c * 16 + m16], psum[c]);
            atomicAdd(&s_sq[c * 16 + m16],  psq[c]);
        }
    }
    __syncthreads();

    // ---- coalesced write-out: 16 lanes cover one 256 B row ----
    {
        const int r0 = tid >> 4;            // 0..15
        const int c0 = (tid & 15) * 8;      // 16 B chunk within row
        #pragma unroll
        for (int it = 0; it < 8; it++) {
            const int rl = r0 + it * 16;
            const u16x8 v = *(const u16x8*)(a_sh + rl * 136 + c0);
            *(u16x8*)(out + (size_t)(base + rl) * 128 + c0) = v;
        }
    }
    if (STATS && tid < 128) {
        atomicAdd(&gsum[tid], s_sum[tid]);
        atomicAdd(&gsq[tid],  s_sq[tid]);
    }
}

// ---------------------------------------------------------------------------
// FUSED: laplacian gather -> A tile in LDS -> MFMA gemm2 -> bias + BN stats.
// Round-6: spill made structurally impossible. The allocator insists on 64
// arch VGPRs for this kernel (r3-r5: attributes ignored, acc[2][8]=64 regs
// alone overflows -> ~500 B/thread scratch). Fix: ROW-SPLIT passes — each
// wave computes ONE row-tile x 8 col-tiles per pass (acc[8]=32 regs), two
// passes (row-tiles wv and 4+wv). A row-tile of a_sh is read only by its
// own wave, so after its k-loop the wave overwrites its own 16 rows with C
// and writes them out wave-locally (no extra LDS, no barrier, coalesced).
// Peak live ~60 regs -> fits 64 budget. LDS 35840 B -> 4 blocks/CU.
// No bounds attributes beyond plain 256. Accumulation order preserved.
// ---------------------------------------------------------------------------
__global__ __launch_bounds__(256) void lap_gemm_kernel(
    const ushort_t* __restrict__ table, const int* __restrict__ idx,
    const ushort_t* __restrict__ wT, const float* __restrict__ bias,
    ushort_t* __restrict__ out, float* __restrict__ gsum, float* __restrict__ gsq)
{
    __shared__ __align__(16) ushort_t a_sh[128 * 136];   // lap tile -> C tile
    __shared__ float s_sum[128];
    __shared__ float s_sq[128];

    const int tid  = threadIdx.x;
    const int lane = tid & 63;
    const int wv   = tid >> 6;
    const int m16  = lane & 15;
    const int q    = lane >> 4;
    const int base = blockIdx.x * 128;

    if (tid < 128) { s_sum[tid] = 0.f; s_sq[tid] = 0.f; }

    // ---- gather + laplacian directly into a_sh (bf16, identical rounding) ----
    {
        const int pl = tid >> 4;                 // 0..15: point-in-group
        const int c8 = (tid & 15) * 8;           // 16 B channel chunk
        const ushort_t* tc = table + c8;
        #pragma unroll 1
        for (int it = 0; it < 8; it++) {
            const int pp = it * 16 + pl;         // local point 0..127
            const size_t prow = (size_t)(base + pp);

            const int4* ig = (const int4*)(idx + prow * NS_K);
            const int4 ia = ig[0];

            const u16x8 cv = *(const u16x8*)(tc + prow * 128);
            float ctr[8];
            #pragma unroll
            for (int e = 0; e < 8; e++) ctr[e] = b2f(cv[e]);
            float lacc[8];
            #pragma unroll
            for (int e = 0; e < 8; e++) lacc[e] = 0.f;

            // ---- s0..s3 in flight; prefetch next index quad meanwhile ----
            const u16x8 n0 = *(const u16x8*)(tc + (size_t)ia.x * 128);
            const u16x8 n1 = *(const u16x8*)(tc + (size_t)ia.y * 128);
            const u16x8 n2 = *(const u16x8*)(tc + (size_t)ia.z * 128);
            const u16x8 n3 = *(const u16x8*)(tc + (size_t)ia.w * 128);
            const int4 ib = ig[1];
            acc8(lacc, ctr, n0); acc8(lacc, ctr, n1);
            acc8(lacc, ctr, n2); acc8(lacc, ctr, n3);

            // ---- s4..s7 ----
            const u16x8 n4 = *(const u16x8*)(tc + (size_t)ib.x * 128);
            const u16x8 n5 = *(const u16x8*)(tc + (size_t)ib.y * 128);
            const u16x8 n6 = *(const u16x8*)(tc + (size_t)ib.z * 128);
            const u16x8 n7 = *(const u16x8*)(tc + (size_t)ib.w * 128);
            const int4 ic = ig[2];
            acc8(lacc, ctr, n4); acc8(lacc, ctr, n5);
            acc8(lacc, ctr, n6); acc8(lacc, ctr, n7);

            // ---- s8..s11 ----
            const u16x8 m0 = *(const u16x8*)(tc + (size_t)ic.x * 128);
            const u16x8 m1 = *(const u16x8*)(tc + (size_t)ic.y * 128);
            const u16x8 m2 = *(const u16x8*)(tc + (size_t)ic.z * 128);
            const u16x8 m3 = *(const u16x8*)(tc + (size_t)ic.w * 128);
            const int4 id = ig[3];
            acc8(lacc, ctr, m0); acc8(lacc, ctr, m1);
            acc8(lacc, ctr, m2); acc8(lacc, ctr, m3);

            // ---- s12..s15 ----
            const u16x8 m4 = *(const u16x8*)(tc + (size_t)id.x * 128);
            const u16x8 m5 = *(const u16x8*)(tc + (size_t)id.y * 128);
            const u16x8 m6 = *(const u16x8*)(tc + (size_t)id.z * 128);
            const u16x8 m7 = *(const u16x8*)(tc + (size_t)id.w * 128);
            acc8(lacc, ctr, m4); acc8(lacc, ctr, m5);
            acc8(lacc, ctr, m6); acc8(lacc, ctr, m7);

            u16x8 ov;
            #pragma unroll
            for (int e = 0; e < 8; e++) ov[e] = f2b(lacc[e] * (1.f / (float)NS_K));
            *(u16x8*)(a_sh + pp * 136 + c8) = ov;
        }
    }
    __syncthreads();

    // ---- MFMA: h = lap @ W2, two row-split passes (acc[8] = 32 regs) ----
    const ushort_t* wp = wT + (size_t)m16 * 128 + q * 8;
    float psum[8], psq[8];
    #pragma unroll
    for (int c = 0; c < 8; c++) { psum[c] = 0.f; psq[c] = 0.f; }

    #pragma unroll 1
    for (int pass = 0; pass < 2; ++pass) {
        const int rt = pass * 4 + wv;            // row-tile 0..7 (16 rows)

        f32x4 acc[8];
        #pragma unroll
        for (int c = 0; c < 8; c++) acc[c] = (f32x4){0.f, 0.f, 0.f, 0.f};

        const ushort_t* ap = a_sh + (rt * 16 + m16) * 136 + q * 8;
        #pragma unroll
        for (int k0 = 0; k0 < 128; k0 += 32) {
            bf16x8 a0 = __builtin_bit_cast(bf16x8, *(const u16x8*)(ap + k0));
            #pragma unroll
            for (int c = 0; c < 8; c++) {
                bf16x8 b = __builtin_bit_cast(bf16x8, *(const u16x8*)(wp + c * (16 * 128) + k0));
                acc[c] = __builtin_amdgcn_mfma_f32_16x16x32_bf16(a0, b, acc[c], 0, 0, 0);
            }
        }

        // ---- epilogue: bias + stats, C overwrites this wave's own 16 rows ----
        // (rows rt*16..rt*16+15 of a_sh are read only by this wave; its k-loop
        //  is complete, so the in-place overwrite is wave-local and safe.)
        #pragma unroll
        for (int c = 0; c < 8; c++) {
            const int col = c * 16 + m16;
            const float bv = bias[col];
            const int rb = rt * 16 + q * 4;
            #pragma unroll
            for (int r = 0; r < 4; r++) {
                const float v = acc[c][r] + bv;
                a_sh[(rb + r) * 136 + col] = f2b(v);
                psum[c] += v; psq[c] += v * v;
            }
        }

        // ---- wave-local coalesced write-out of this row-tile ----
        {
            const int r0 = lane >> 4;            // 0..3
            const int c0 = m16 * 8;              // 16 B chunk within row
            #pragma unroll
            for (int it = 0; it < 4; it++) {
                const int rl = rt * 16 + it * 4 + r0;
                const u16x8 v = *(const u16x8*)(a_sh + rl * 136 + c0);
                *(u16x8*)(out + (size_t)(base + rl) * 128 + c0) = v;
            }
        }
    }

    // ---- BN stats reduction ----
    #pragma unroll
    for (int c = 0; c < 8; c++) {
        atomicAdd(&s_sum[c * 16 + m16], psum[c]);
        atomicAdd(&s_sq[c * 16 + m16],  psq[c]);
    }
    __syncthreads();
    if (tid < 128) {
        atomicAdd(&gsum[tid], s_sum[tid]);
        atomicAdd(&gsq[tid],  s_sq[tid]);
    }
}

// ---------------------------------------------------------------------------
// Fold BN stats into per-channel scale/shift (1 block, 128 threads).
// ---------------------------------------------------------------------------
__global__ void bn_stats_kernel(const float* __restrict__ gsum,
                                const float* __restrict__ gsq,
                                const float* __restrict__ gamma,
                                const float* __restrict__ beta,
                                float* __restrict__ bnsc, float* __restrict__ bnsh)
{
    const int c = threadIdx.x;
    const float invN = 1.f / (float)N_PTS;
    const float mean = gsum[c] * invN;
    const float var  = gsq[c] * invN - mean * mean;
    const float sc   = rsqrtf(var + BN_EPS) * gamma[c];
    bnsc[c] = sc;
    bnsh[c] = fmaf(-mean, sc, beta[c]);
}

// ---------------------------------------------------------------------------
// FUSED: BN apply + ReLU (blocks [0,8192)) and p/o copy (blocks [8192,8576)).
// ---------------------------------------------------------------------------
#define BN_BLOCKS ((N_PTS * C_DIM / 8) / 256)   // 8192
#define P_BLOCKS  ((3 * N_PTS / 4) / 256)       // 384

__global__ __launch_bounds__(256) void bn_relu_p_kernel(
    const ushort_t* __restrict__ h, const float* __restrict__ bnsc,
    const float* __restrict__ bnsh, const float* __restrict__ p,
    const int* __restrict__ o, float* __restrict__ out)
{
    const int b = blockIdx.x;
    if (b < BN_BLOCKS) {
        const size_t i = (size_t)b * 256 + threadIdx.x;
        const int c8 = (threadIdx.x * 8) & 127;   // block covers 16 full rows

        const u16x8 hv = *(const u16x8*)(h + i * 8);
        const f32x4 sc0 = *(const f32x4*)(bnsc + c8);
        const f32x4 sc1 = *(const f32x4*)(bnsc + c8 + 4);
        const f32x4 sh0 = *(const f32x4*)(bnsh + c8);
        const f32x4 sh1 = *(const f32x4*)(bnsh + c8 + 4);

        f32x4 o0, o1;
        #pragma unroll
        for (int e = 0; e < 4; e++) {
            o0[e] = fmaxf(fmaf(b2f(hv[e]),     sc0[e], sh0[e]), 0.f);
            o1[e] = fmaxf(fmaf(b2f(hv[4 + e]), sc1[e], sh1[e]), 0.f);
        }
        float* op = out + (size_t)3 * N_PTS + i * 8;
        *(f32x4*)(op)     = o0;
        *(f32x4*)(op + 4) = o1;
    } else {
        const size_t i = (size_t)(b - BN_BLOCKS) * 256 + threadIdx.x;
        *(f32x4*)(out + i * 4) = *(const f32x4*)(p + i * 4);
        if (i == 0)
            out[(size_t)3 * N_PTS + (size_t)N_PTS * C_DIM] = (float)o[0];
    }
}

extern "C" void kernel_launch(void* const* d_in, const int* in_sizes, int n_in,
                              void* d_out, int out_size, void* d_ws, size_t ws_size,
                              hipStream_t stream) {
    const float* p     = (const float*)d_in[0];
    const float* u     = (const float*)d_in[1];
    const int*   o     = (const int*)d_in[2];
    const int*   idx   = (const int*)d_in[3];
    const float* W1    = (const float*)d_in[4];
    const float* b1    = (const float*)d_in[5];
    const float* W2    = (const float*)d_in[6];
    const float* b2    = (const float*)d_in[7];
    const float* gamma = (const float*)d_in[8];
    const float* beta  = (const float*)d_in[9];
    float* out = (float*)d_out;

    char* ws = (char*)d_ws;
    const size_t buf_bytes = (size_t)N_PTS * C_DIM * sizeof(ushort_t);  // 32 MB
    ushort_t* table = (ushort_t*)ws;                       // u_pre, bf16
    ushort_t* h     = (ushort_t*)(ws + buf_bytes);         // pre-BN, bf16
    float*    stats = (float*)(ws + 2 * buf_bytes);
    float* gsum = stats;        // [128]
    float* gsq  = stats + 128;  // [128]
    float* bnsc = stats + 256;  // [128]
    float* bnsh = stats + 384;  // [128]
    ushort_t* wT1 = (ushort_t*)(stats + 512);              // [128*128] bf16
    ushort_t* wT2 = wT1 + 128 * 128;

    hipMemsetAsync(stats, 0, 256 * sizeof(float), stream);

    prep_w_kernel<<<64, 256, 0, stream>>>(W1, W2, wT1, wT2);
    gemm_mfma_kernel<false, false><<<N_PTS / 128, 256, 0, stream>>>(
        u, wT1, b1, table, nullptr, nullptr);
    lap_gemm_kernel<<<N_PTS / 128, 256, 0, stream>>>(
        table, idx, wT2, b2, h, gsum, gsq);
    bn_stats_kernel<<<1, 128, 0, stream>>>(gsum, gsq, gamma, beta, bnsc, bnsh);
    bn_relu_p_kernel<<<BN_BLOCKS + P_BLOCKS, 256, 0, stream>>>(
        h, bnsc, bnsh, p, o, out);
}